// Round 6
// baseline (1334.317 us; speedup 1.0000x reference)
//
#include <hip/hip_runtime.h>
#include <cstdint>
#include <cstddef>

// Problem constants
#define NBATCH 8
#define NNODE  20000
#define TWO_E  640000            // 2*E
#define NEDGE  2560000           // B*E total edges after the reshape quirk
#define BN     160000            // B*N nodes
#define HN     80000             // dst nodes (batches 4..7), src nodes (0..3)
#define HID    128
#define EMB    64

#define NB     625               // dst bins: d4 >> 7, 128 dsts/bin (625*128 = 80000 exact)
#define NWG    320               // WGs for hist/place; chunk = 8000 edges (320*8000 = NEDGE exact)
#define CHUNK  8000

// Workspace layout (bytes). Only pool is zeroed.
#define OFF_POOL     0ull               // 8*64*4 = 2,048
#define ZERO_BYTES   2048ull
#define OFF_CNT      2048ull            // [625][320] int = 800,000 (hist, then in-place excl scan)
#define OFF_TOTAL    802048ull          // 625*4 (pad 2,560)
#define OFF_BSTART   804608ull          // 625*4 (pad 2,560)
#define OFF_BINS     807168ull          // 2,560,000*4 = 10,240,000 (packed (d4<<15)|sn, sorted by bin)
#define OFF_AGG1F    11047168ull        // 80000*3*4 = 960,000 (fp32)
#define OFF_AGG2     12007168ull        // 80000*64*2 = 10,240,000 (bf16)
#define OFF_X1       22247168ull        // 160000*64*2 = 20,480,000 (bf16)
#define OFF_W1T1     42727168ull        // 128*3*4
#define OFF_W1HI     42728704ull        // 16,384
#define OFF_W2HI     42745088ull        // 16,384
#define OFF_W1LO     42761472ull        // 16,384
#define OFF_W2LO     42777856ull        // 16,384
#define OFF_Q        42794240ull        // 4,096
// total: 42,798,336 bytes

using bf16x8 = __attribute__((ext_vector_type(8))) short;
using f32x4  = __attribute__((ext_vector_type(4))) float;

__device__ __forceinline__ float bf2f(unsigned short u) {
    union { unsigned int i; float f; } v; v.i = ((unsigned int)u) << 16; return v.f;
}
__device__ __forceinline__ unsigned short f2bf(float x) {
    union { float f; unsigned int i; } v; v.f = x;
    unsigned int r = v.i + 0x7FFF + ((v.i >> 16) & 1);   // round-to-nearest-even
    return (unsigned short)(r >> 16);
}
__device__ __forceinline__ unsigned int addbf2(unsigned int a, unsigned int b) {
    float lo = bf2f((unsigned short)(a & 0xFFFF)) + bf2f((unsigned short)(b & 0xFFFF));
    float hi = bf2f((unsigned short)(a >> 16))    + bf2f((unsigned short)(b >> 16));
    return (unsigned int)f2bf(lo) | ((unsigned int)f2bf(hi) << 16);
}

// ---- weight prep (unchanged from round 5)
__global__ void k_transpose(const float* __restrict__ w1, const float* __restrict__ w2,
                            const float* __restrict__ w2b,
                            float* __restrict__ w1t,
                            unsigned short* __restrict__ w1hi, unsigned short* __restrict__ w2hi,
                            unsigned short* __restrict__ w1lo, unsigned short* __restrict__ w2lo) {
    int t = blockIdx.x * blockDim.x + threadIdx.x;
    int stride = gridDim.x * blockDim.x;
    for (int i = t; i < 3 * 128; i += stride) {
        int k = i / 128, j = i % 128;
        w1t[j * 3 + k] = w1[i];
    }
    for (int i = t; i < 128 * 64; i += stride) {     // w1hi[n][k] = bf16(c2_w1[k][n])
        int n = i >> 6, k = i & 63;
        w1hi[i] = f2bf(w2[k * 128 + n]);
    }
    for (int i = t; i < 64 * 128; i += stride) {     // w2hi[n][k] = bf16(c2_w2[k][n])
        int n = i >> 7, k = i & 127;
        w2hi[i] = f2bf(w2b[k * 64 + n]);
    }
    for (int i = t; i < 8192; i += stride) {         // W1 lo residual, frag-swizzled
        int j = i & 7, l = (i >> 3) & 63, fid = i >> 9;
        int n16 = fid >> 1, ks = fid & 1;
        int n = n16 * 16 + (l & 15), k = ks * 32 + (l >> 4) * 8 + j;
        float w = w2[k * 128 + n];
        w1lo[i] = f2bf(w - bf2f(f2bf(w)));
    }
    for (int i = t; i < 8192; i += stride) {         // W2 lo residual, frag-swizzled
        int j = i & 7, l = (i >> 3) & 63, fid = i >> 9;
        int n16 = fid >> 2, ks = fid & 3;
        int n = n16 * 16 + (l & 15), k = ks * 32 + (l >> 4) * 8 + j;
        float w = w2b[k * 64 + n];
        w2lo[i] = f2bf(w - bf2f(f2bf(w)));
    }
}

// ---- pass 1: per-WG histogram over 625 dst bins (LDS privatized)
__global__ __launch_bounds__(256) void k_hist(const int* __restrict__ ei,
                                              int* __restrict__ cnt) {   // [bin][wg]
    __shared__ int hist[NB];
    int tid = threadIdx.x, w = blockIdx.x;
    for (int b = tid; b < NB; b += 256) hist[b] = 0;
    __syncthreads();
    for (int i = tid; i < CHUNK; i += 256) {
        int ig = w * CHUNK + i;
        int b = ig / TWO_E;
        int j = ig - b * TWO_E;
        int d4 = b * NNODE + ei[(b + 4) * TWO_E + j];
        atomicAdd(&hist[d4 >> 7], 1);
    }
    __syncthreads();
    for (int b = tid; b < NB; b += 256) cnt[b * NWG + w] = hist[b];
}

// ---- pass 2a: per-bin exclusive scan over the 320 WG counts (in-place), totals out
__global__ __launch_bounds__(64) void k_scanA(int* __restrict__ cnt,      // [bin][wg]
                                              int* __restrict__ total) {
    int b = blockIdx.x, lane = threadIdx.x;
    int w0 = lane * 5;
    int v[5], c[5], s = 0;
#pragma unroll
    for (int k = 0; k < 5; ++k) v[k] = cnt[b * NWG + w0 + k];
#pragma unroll
    for (int k = 0; k < 5; ++k) { c[k] = s; s += v[k]; }
    int inc = s;
#pragma unroll
    for (int off = 1; off < 64; off <<= 1) {
        int t = __shfl_up(inc, off, 64);
        if (lane >= off) inc += t;
    }
    int excl = inc - s;
#pragma unroll
    for (int k = 0; k < 5; ++k) cnt[b * NWG + w0 + k] = excl + c[k];
    if (lane == 63) total[b] = excl + s;
}

// ---- pass 2b: exclusive scan over the 625 bin totals
__global__ __launch_bounds__(1024) void k_scanB(const int* __restrict__ total,
                                                int* __restrict__ binStart) {
    __shared__ int tmp[1024];
    int tid = threadIdx.x;
    int v = (tid < NB) ? total[tid] : 0;
    tmp[tid] = v;
    __syncthreads();
    for (int off = 1; off < 1024; off <<= 1) {
        int t = (tid >= off) ? tmp[tid - off] : 0;
        __syncthreads();
        tmp[tid] += t;
        __syncthreads();
    }
    if (tid < NB) binStart[tid] = tmp[tid] - v;
}

// ---- pass 3: place packed edges at exact offsets (LDS cursors; writes stay L2-resident)
__global__ __launch_bounds__(256) void k_place(const int* __restrict__ ei,
                                               const int* __restrict__ cnt,      // excl-scanned
                                               const int* __restrict__ binStart,
                                               unsigned int* __restrict__ bins) {
    __shared__ int cur[NB];
    int tid = threadIdx.x, w = blockIdx.x;
    for (int b = tid; b < NB; b += 256) cur[b] = binStart[b] + cnt[b * NWG + w];
    __syncthreads();
    for (int i = tid; i < CHUNK; i += 256) {
        int ig = w * CHUNK + i;
        int b = ig / TWO_E;
        int j = ig - b * TWO_E;
        int sn = ei[b * TWO_E + j];
        int d4 = b * NNODE + ei[(b + 4) * TWO_E + j];
        unsigned int e = ((unsigned int)d4 << 15) | (unsigned int)sn;
        int pos = atomicAdd(&cur[d4 >> 7], 1);
        bins[pos] = e;
    }
}

// ---- agg1: per-bin LDS accumulation of x0 (3 features) -> agg1f fp32
__global__ __launch_bounds__(256) void k_agg1(const unsigned int* __restrict__ bins,
                                              const int* __restrict__ binStart,
                                              const int* __restrict__ total,
                                              const float* __restrict__ actions,
                                              const float* __restrict__ nf,
                                              float* __restrict__ agg1f) {
    __shared__ float acc[128 * 3];
    int tid = threadIdx.x, bin = blockIdx.x;
    for (int i = tid; i < 384; i += 256) acc[i] = 0.0f;
    __syncthreads();
    int start = binStart[bin], end = start + total[bin];
    const float2* act2 = reinterpret_cast<const float2*>(actions);
    for (int p = start + tid; p < end; p += 256) {
        unsigned int e = bins[p];
        int d4 = e >> 15, sn = e & 0x7FFF;
        int s = (d4 / NNODE) * NNODE + sn;
        float2 a = act2[s];
        float nv = nf[s];
        int r = (d4 & 127) * 3;
        atomicAdd(&acc[r + 0], a.x);
        atomicAdd(&acc[r + 1], a.y);
        atomicAdd(&acc[r + 2], nv);
    }
    __syncthreads();
    for (int i = tid; i < 384; i += 256) agg1f[bin * 384 + i] = acc[i];
}

// ---- conv1 MLP (pure, agg1 pre-computed); x1 stored bf16
__global__ __launch_bounds__(256) void k_conv1(const float* __restrict__ actions,
                                               const float* __restrict__ nf,
                                               const float* __restrict__ agg1f,
                                               const float* __restrict__ w1t, // [128][3]
                                               const float* __restrict__ b1,
                                               const float* __restrict__ w2,  // [128][64]
                                               const float* __restrict__ b2,
                                               unsigned short* __restrict__ x1) {
    int t = blockIdx.x * blockDim.x + threadIdx.x;
    if (t >= BN) return;
    const float2* act2 = reinterpret_cast<const float2*>(actions);
    float2 a = act2[t];
    float h0 = a.x, h1 = a.y, h2 = nf[t];
    if (t >= HN) {
        int d4 = t - HN;
        h0 += agg1f[d4 * 3 + 0];
        h1 += agg1f[d4 * 3 + 1];
        h2 += agg1f[d4 * 3 + 2];
    }

    float acc[64];
#pragma unroll
    for (int o = 0; o < 64; ++o) acc[o] = b2[o];

#pragma unroll 2
    for (int j = 0; j < HID; ++j) {
        float hj = fmaf(h0, w1t[3 * j + 0],
                   fmaf(h1, w1t[3 * j + 1],
                   fmaf(h2, w1t[3 * j + 2], b1[j])));
        hj = fmaxf(hj, 0.0f);
        const float* w2r = w2 + j * 64;
#pragma unroll
        for (int o = 0; o < 64; ++o) acc[o] = fmaf(hj, w2r[o], acc[o]);
    }
    uint4* xo = reinterpret_cast<uint4*>(x1 + (size_t)t * 64);
#pragma unroll
    for (int g = 0; g < 8; ++g) {
        uint4 v;
        v.x = f2bf(fmaxf(acc[8 * g + 0], 0.f)) | ((unsigned int)f2bf(fmaxf(acc[8 * g + 1], 0.f)) << 16);
        v.y = f2bf(fmaxf(acc[8 * g + 2], 0.f)) | ((unsigned int)f2bf(fmaxf(acc[8 * g + 3], 0.f)) << 16);
        v.z = f2bf(fmaxf(acc[8 * g + 4], 0.f)) | ((unsigned int)f2bf(fmaxf(acc[8 * g + 5], 0.f)) << 16);
        v.w = f2bf(fmaxf(acc[8 * g + 6], 0.f)) | ((unsigned int)f2bf(fmaxf(acc[8 * g + 7], 0.f)) << 16);
        xo[g] = v;
    }
}

// ---- agg2: per-bin LDS accumulation of x1 rows (wave-per-edge, lane=feature) -> agg2 bf16
__global__ __launch_bounds__(512) void k_agg2(const unsigned int* __restrict__ bins,
                                              const int* __restrict__ binStart,
                                              const int* __restrict__ total,
                                              const unsigned short* __restrict__ x1,
                                              unsigned short* __restrict__ agg2) {
    __shared__ float acc[128 * 64];   // 32 KB; bank(f) = f%32, 2-way per wave = free
    int tid = threadIdx.x, bin = blockIdx.x;
    int lane = tid & 63, wv = tid >> 6;     // 8 waves
    for (int i = tid; i < 8192; i += 512) acc[i] = 0.0f;
    __syncthreads();
    int start = binStart[bin], cntN = total[bin];
    int sub = (cntN + 7) >> 3;
    int a0 = start + wv * sub;
    int a1 = a0 + sub; { int e = start + cntN; if (a1 > e) a1 = e; }
    int p = a0;
    for (; p + 4 <= a1; p += 4) {
        unsigned int e0 = bins[p], e1 = bins[p + 1], e2 = bins[p + 2], e3 = bins[p + 3];
        int d0 = e0 >> 15, d1 = e1 >> 15, d2 = e2 >> 15, d3 = e3 >> 15;
        int s0 = (d0 / NNODE) * NNODE + (e0 & 0x7FFF);
        int s1 = (d1 / NNODE) * NNODE + (e1 & 0x7FFF);
        int s2 = (d2 / NNODE) * NNODE + (e2 & 0x7FFF);
        int s3 = (d3 / NNODE) * NNODE + (e3 & 0x7FFF);
        float v0 = bf2f(x1[(size_t)s0 * 64 + lane]);
        float v1 = bf2f(x1[(size_t)s1 * 64 + lane]);
        float v2 = bf2f(x1[(size_t)s2 * 64 + lane]);
        float v3 = bf2f(x1[(size_t)s3 * 64 + lane]);
        atomicAdd(&acc[(d0 & 127) * 64 + lane], v0);
        atomicAdd(&acc[(d1 & 127) * 64 + lane], v1);
        atomicAdd(&acc[(d2 & 127) * 64 + lane], v2);
        atomicAdd(&acc[(d3 & 127) * 64 + lane], v3);
    }
    for (; p < a1; ++p) {
        unsigned int e = bins[p];
        int d4 = e >> 15;
        int s = (d4 / NNODE) * NNODE + (e & 0x7FFF);
        atomicAdd(&acc[(d4 & 127) * 64 + lane], bf2f(x1[(size_t)s * 64 + lane]));
    }
    __syncthreads();
    for (int i = tid; i < 8192; i += 512) agg2[(size_t)bin * 8192 + i] = f2bf(acc[i]);
}

// ---- conv2 MLP + global sum pool, MFMA hi/lo (unchanged from round 5, verified)
__global__ __launch_bounds__(256) void k_conv2pool(const unsigned short* __restrict__ x1,
                                                   const unsigned short* __restrict__ agg2,
                                                   const unsigned short* __restrict__ w1hi,
                                                   const unsigned short* __restrict__ w1lo,
                                                   const unsigned short* __restrict__ w2hi,
                                                   const unsigned short* __restrict__ w2lo,
                                                   const float* __restrict__ b1,
                                                   const float* __restrict__ b2,
                                                   float* __restrict__ pool) {
    __shared__ __align__(16) unsigned short Hs[32][72];
    __shared__ __align__(16) unsigned short W1s[128][72];
    __shared__ __align__(16) unsigned short Hid[32][136];
    __shared__ __align__(16) unsigned short W2s[64][136];
    __shared__ float poolLDS[64];

    const int tid  = threadIdx.x;
    const int lane = tid & 63;
    const int wv   = tid >> 6;
    const int quad = lane >> 4;
    const int l16  = lane & 15;

    const int m0 = blockIdx.x * 32;
    const int b  = m0 / NNODE;

    if (tid < 64) poolLDS[tid] = 0.0f;

    {
        int row = tid >> 3, g = tid & 7;
        const uint4* xr = reinterpret_cast<const uint4*>(x1 + (size_t)(m0 + row) * 64 + g * 8);
        uint4 v = *xr;
        if (m0 >= HN) {
            const uint4* ar = reinterpret_cast<const uint4*>(agg2 + (size_t)(m0 - HN + row) * 64 + g * 8);
            uint4 a = *ar;
            v.x = addbf2(v.x, a.x); v.y = addbf2(v.y, a.y);
            v.z = addbf2(v.z, a.z); v.w = addbf2(v.w, a.w);
        }
        *reinterpret_cast<uint4*>(&Hs[row][g * 8]) = v;
    }
    for (int i = tid; i < 1024; i += 256) {
        *reinterpret_cast<uint4*>(&W1s[i >> 3][(i & 7) * 8]) =
            reinterpret_cast<const uint4*>(w1hi)[i];
    }
    for (int i = tid; i < 1024; i += 256) {
        *reinterpret_cast<uint4*>(&W2s[i >> 4][(i & 15) * 8]) =
            reinterpret_cast<const uint4*>(w2hi)[i];
    }
    __syncthreads();

    {
        const int mt = wv & 1;
        const int nb = (wv >> 1) * 64;
        f32x4 acc[4];
#pragma unroll
        for (int nt = 0; nt < 4; ++nt) acc[nt] = {0.f, 0.f, 0.f, 0.f};
#pragma unroll
        for (int ks = 0; ks < 2; ++ks) {
            bf16x8 a = *reinterpret_cast<const bf16x8*>(&Hs[mt * 16 + l16][ks * 32 + quad * 8]);
#pragma unroll
            for (int nt = 0; nt < 4; ++nt) {
                int fid = ((nb >> 4) + nt) * 2 + ks;
                bf16x8 bhi = *reinterpret_cast<const bf16x8*>(&W1s[nb + nt * 16 + l16][ks * 32 + quad * 8]);
                bf16x8 blo = *reinterpret_cast<const bf16x8*>(&w1lo[(size_t)(fid * 64 + lane) * 8]);
                acc[nt] = __builtin_amdgcn_mfma_f32_16x16x32_bf16(a, bhi, acc[nt], 0, 0, 0);
                acc[nt] = __builtin_amdgcn_mfma_f32_16x16x32_bf16(a, blo, acc[nt], 0, 0, 0);
            }
        }
#pragma unroll
        for (int nt = 0; nt < 4; ++nt) {
            int n = nb + nt * 16 + l16;
            float bias = b1[n];
#pragma unroll
            for (int r = 0; r < 4; ++r) {
                int m = mt * 16 + quad * 4 + r;
                Hid[m][n] = f2bf(fmaxf(acc[nt][r] + bias, 0.0f));
            }
        }
    }
    __syncthreads();

    {
        const int mt = wv & 1;
        const int nb = (wv >> 1) * 32;
        f32x4 acc[2];
#pragma unroll
        for (int nt = 0; nt < 2; ++nt) acc[nt] = {0.f, 0.f, 0.f, 0.f};
#pragma unroll
        for (int ks = 0; ks < 4; ++ks) {
            bf16x8 a = *reinterpret_cast<const bf16x8*>(&Hid[mt * 16 + l16][ks * 32 + quad * 8]);
#pragma unroll
            for (int nt = 0; nt < 2; ++nt) {
                int fid = ((nb >> 4) + nt) * 4 + ks;
                bf16x8 bhi = *reinterpret_cast<const bf16x8*>(&W2s[nb + nt * 16 + l16][ks * 32 + quad * 8]);
                bf16x8 blo = *reinterpret_cast<const bf16x8*>(&w2lo[(size_t)(fid * 64 + lane) * 8]);
                acc[nt] = __builtin_amdgcn_mfma_f32_16x16x32_bf16(a, bhi, acc[nt], 0, 0, 0);
                acc[nt] = __builtin_amdgcn_mfma_f32_16x16x32_bf16(a, blo, acc[nt], 0, 0, 0);
            }
        }
#pragma unroll
        for (int nt = 0; nt < 2; ++nt) {
            int n = nb + nt * 16 + l16;
            float bias = b2[n];
            float p = 0.0f;
#pragma unroll
            for (int r = 0; r < 4; ++r) p += fmaxf(acc[nt][r] + bias, 0.0f);
            p += __shfl_xor(p, 16, 64);
            p += __shfl_xor(p, 32, 64);
            if (lane < 16) atomicAdd(&poolLDS[n], p);
        }
    }
    __syncthreads();

    if (tid < 64) atomicAdd(&pool[b * 64 + tid], poolLDS[tid]);
}

// ---- q = relu(pool @ mlp_w + mlp_b)  [8,128]
__global__ __launch_bounds__(128) void k_q(const float* __restrict__ pool,
                                           const float* __restrict__ mlp_w,
                                           const float* __restrict__ mlp_b,
                                           float* __restrict__ q) {
    int j = threadIdx.x;
    for (int b = 0; b < NBATCH; ++b) {
        float a = mlp_b[j];
#pragma unroll 8
        for (int k = 0; k < 64; ++k) a = fmaf(pool[b * 64 + k], mlp_w[k * 128 + j], a);
        q[b * 128 + j] = fmaxf(a, 0.0f);
    }
}

// ---- out = sigmoid(q @ out_w + out_b)  [8,20000]
__global__ __launch_bounds__(256) void k_out(const float* __restrict__ q,
                                             const float* __restrict__ out_w,
                                             const float* __restrict__ out_b,
                                             float* __restrict__ out) {
    __shared__ float qs[2][128];
    int b0 = (blockIdx.x * blockDim.x) / NNODE;
    for (int i = threadIdx.x; i < 256; i += blockDim.x) {
        int s = i >> 7;
        if (b0 + s < NBATCH) qs[s][i & 127] = q[(b0 + s) * 128 + (i & 127)];
    }
    __syncthreads();
    int t = blockIdx.x * blockDim.x + threadIdx.x;
    int b = t / NNODE;
    int n = t - b * NNODE;
    const float* qr = qs[b - b0];
    float a = out_b[n];
#pragma unroll 8
    for (int j = 0; j < 128; ++j) a = fmaf(qr[j], out_w[j * NNODE + n], a);
    out[t] = 1.0f / (1.0f + expf(-a));
}

extern "C" void kernel_launch(void* const* d_in, const int* in_sizes, int n_in,
                              void* d_out, int out_size, void* d_ws, size_t ws_size,
                              hipStream_t stream) {
    const float* actions = (const float*)d_in[0];
    const float* nf      = (const float*)d_in[1];
    const int*   ei      = (const int*)d_in[2];
    const float* c1_w1   = (const float*)d_in[3];
    const float* c1_b1   = (const float*)d_in[4];
    const float* c1_w2   = (const float*)d_in[5];
    const float* c1_b2   = (const float*)d_in[6];
    const float* c2_w1   = (const float*)d_in[7];
    const float* c2_b1   = (const float*)d_in[8];
    const float* c2_w2   = (const float*)d_in[9];
    const float* c2_b2   = (const float*)d_in[10];
    const float* mlp_w   = (const float*)d_in[11];
    const float* mlp_b   = (const float*)d_in[12];
    const float* out_w   = (const float*)d_in[13];
    const float* out_b   = (const float*)d_in[14];
    float* out = (float*)d_out;

    char* ws = (char*)d_ws;
    float*        pool     = (float*)(ws + OFF_POOL);
    int*          cnt      = (int*)(ws + OFF_CNT);
    int*          total    = (int*)(ws + OFF_TOTAL);
    int*          binStart = (int*)(ws + OFF_BSTART);
    unsigned int* bins     = (unsigned int*)(ws + OFF_BINS);
    float*        agg1f    = (float*)(ws + OFF_AGG1F);
    unsigned short* agg2   = (unsigned short*)(ws + OFF_AGG2);
    unsigned short* x1     = (unsigned short*)(ws + OFF_X1);
    float* w1t1 = (float*)(ws + OFF_W1T1);
    unsigned short* w1hi = (unsigned short*)(ws + OFF_W1HI);
    unsigned short* w2hi = (unsigned short*)(ws + OFF_W2HI);
    unsigned short* w1lo = (unsigned short*)(ws + OFF_W1LO);
    unsigned short* w2lo = (unsigned short*)(ws + OFF_W2LO);
    float* q = (float*)(ws + OFF_Q);

    hipMemsetAsync(d_ws, 0, ZERO_BYTES, stream);   // pool only

    k_transpose<<<32, 256, 0, stream>>>(c1_w1, c2_w1, c2_w2, w1t1, w1hi, w2hi, w1lo, w2lo);

    // counting-sort of edges into 625 dst bins (exact offsets, no global atomics on hot lines)
    k_hist <<<NWG, 256, 0, stream>>>(ei, cnt);
    k_scanA<<<NB, 64, 0, stream>>>(cnt, total);
    k_scanB<<<1, 1024, 0, stream>>>(total, binStart);
    k_place<<<NWG, 256, 0, stream>>>(ei, cnt, binStart, bins);

    // aggregations from sorted bins (LDS-privatized), then MLPs
    k_agg1<<<NB, 256, 0, stream>>>(bins, binStart, total, actions, nf, agg1f);
    k_conv1<<<BN / 256, 256, 0, stream>>>(actions, nf, agg1f, w1t1, c1_b1, c1_w2, c1_b2, x1);
    k_agg2<<<NB, 512, 0, stream>>>(bins, binStart, total, x1, agg2);

    k_conv2pool<<<BN / 32, 256, 0, stream>>>(x1, agg2, w1hi, w1lo, w2hi, w2lo,
                                             c2_b1, c2_b2, pool);

    k_q<<<1, 128, 0, stream>>>(pool, mlp_w, mlp_b, q);
    k_out<<<BN / 256, 256, 0, stream>>>(q, out_w, out_b, out);
}

// Round 7
// 529.833 us; speedup vs baseline: 2.5184x; 2.5184x over previous
//
#include <hip/hip_runtime.h>
#include <cstdint>
#include <cstddef>

// Problem constants
#define NBATCH 8
#define NNODE  20000
#define TWO_E  640000            // 2*E
#define NEDGE  2560000           // B*E total edges after the reshape quirk
#define BN     160000            // B*N nodes
#define HN     80000             // dst nodes (batches 4..7), src nodes (0..3)
#define HID    128
#define EMB    64

#define NB     625               // dst bins: d4 >> 7, 128 dsts/bin (625*128 = 80000 exact)
#define NWG    320               // WGs for hist/place; chunk = 8000 edges (320*8000 = NEDGE exact)
#define CHUNK  8000

// Workspace layout (bytes). Only pool is zeroed.
#define OFF_POOL     0ull               // 8*64*4 = 2,048
#define ZERO_BYTES   2048ull
#define OFF_CNT      2048ull            // [625][320] int = 800,000 (hist, then in-place excl scan)
#define OFF_TOTAL    802048ull          // 625*4 (pad 2,560)
#define OFF_BSTART   804608ull          // 625*4 (pad 2,560)
#define OFF_BINS     807168ull          // 2,560,000*4 = 10,240,000 (packed (d4<<15)|sn, sorted by bin)
#define OFF_AGG1F    11047168ull        // 80000*3*4 = 960,000 (fp32)
#define OFF_AGG2     12007168ull        // 80000*64*2 = 10,240,000 (bf16)
#define OFF_X1       22247168ull        // 160000*64*2 = 20,480,000 (bf16)
#define OFF_W1T1     42727168ull        // 128*3*4
#define OFF_W1HI     42728704ull        // 16,384
#define OFF_W2HI     42745088ull        // 16,384
#define OFF_W1LO     42761472ull        // 16,384
#define OFF_W2LO     42777856ull        // 16,384
#define OFF_Q        42794240ull        // 4,096
// total: 42,798,336 bytes

using bf16x8 = __attribute__((ext_vector_type(8))) short;
using f32x4  = __attribute__((ext_vector_type(4))) float;

__device__ __forceinline__ float bf2f(unsigned short u) {
    union { unsigned int i; float f; } v; v.i = ((unsigned int)u) << 16; return v.f;
}
__device__ __forceinline__ unsigned short f2bf(float x) {
    union { float f; unsigned int i; } v; v.f = x;
    unsigned int r = v.i + 0x7FFF + ((v.i >> 16) & 1);   // round-to-nearest-even
    return (unsigned short)(r >> 16);
}
__device__ __forceinline__ unsigned int addbf2(unsigned int a, unsigned int b) {
    float lo = bf2f((unsigned short)(a & 0xFFFF)) + bf2f((unsigned short)(b & 0xFFFF));
    float hi = bf2f((unsigned short)(a >> 16))    + bf2f((unsigned short)(b >> 16));
    return (unsigned int)f2bf(lo) | ((unsigned int)f2bf(hi) << 16);
}

// ---- weight prep (unchanged)
__global__ void k_transpose(const float* __restrict__ w1, const float* __restrict__ w2,
                            const float* __restrict__ w2b,
                            float* __restrict__ w1t,
                            unsigned short* __restrict__ w1hi, unsigned short* __restrict__ w2hi,
                            unsigned short* __restrict__ w1lo, unsigned short* __restrict__ w2lo) {
    int t = blockIdx.x * blockDim.x + threadIdx.x;
    int stride = gridDim.x * blockDim.x;
    for (int i = t; i < 3 * 128; i += stride) {
        int k = i / 128, j = i % 128;
        w1t[j * 3 + k] = w1[i];
    }
    for (int i = t; i < 128 * 64; i += stride) {     // w1hi[n][k] = bf16(c2_w1[k][n])
        int n = i >> 6, k = i & 63;
        w1hi[i] = f2bf(w2[k * 128 + n]);
    }
    for (int i = t; i < 64 * 128; i += stride) {     // w2hi[n][k] = bf16(c2_w2[k][n])
        int n = i >> 7, k = i & 127;
        w2hi[i] = f2bf(w2b[k * 64 + n]);
    }
    for (int i = t; i < 8192; i += stride) {         // W1 lo residual, frag-swizzled
        int j = i & 7, l = (i >> 3) & 63, fid = i >> 9;
        int n16 = fid >> 1, ks = fid & 1;
        int n = n16 * 16 + (l & 15), k = ks * 32 + (l >> 4) * 8 + j;
        float w = w2[k * 128 + n];
        w1lo[i] = f2bf(w - bf2f(f2bf(w)));
    }
    for (int i = t; i < 8192; i += stride) {         // W2 lo residual, frag-swizzled
        int j = i & 7, l = (i >> 3) & 63, fid = i >> 9;
        int n16 = fid >> 2, ks = fid & 3;
        int n = n16 * 16 + (l & 15), k = ks * 32 + (l >> 4) * 8 + j;
        float w = w2b[k * 64 + n];
        w2lo[i] = f2bf(w - bf2f(f2bf(w)));
    }
}

// ---- pass 1: per-WG histogram over 625 dst bins (LDS privatized; int atomics, low volume)
__global__ __launch_bounds__(256) void k_hist(const int* __restrict__ ei,
                                              int* __restrict__ cnt) {   // [bin][wg]
    __shared__ int hist[NB];
    int tid = threadIdx.x, w = blockIdx.x;
    for (int b = tid; b < NB; b += 256) hist[b] = 0;
    __syncthreads();
    for (int i = tid; i < CHUNK; i += 256) {
        int ig = w * CHUNK + i;
        int b = ig / TWO_E;
        int j = ig - b * TWO_E;
        int d4 = b * NNODE + ei[(b + 4) * TWO_E + j];
        atomicAdd(&hist[d4 >> 7], 1);
    }
    __syncthreads();
    for (int b = tid; b < NB; b += 256) cnt[b * NWG + w] = hist[b];
}

// ---- pass 2a: per-bin exclusive scan over the 320 WG counts (in-place), totals out
__global__ __launch_bounds__(64) void k_scanA(int* __restrict__ cnt,      // [bin][wg]
                                              int* __restrict__ total) {
    int b = blockIdx.x, lane = threadIdx.x;
    int w0 = lane * 5;
    int v[5], c[5], s = 0;
#pragma unroll
    for (int k = 0; k < 5; ++k) v[k] = cnt[b * NWG + w0 + k];
#pragma unroll
    for (int k = 0; k < 5; ++k) { c[k] = s; s += v[k]; }
    int inc = s;
#pragma unroll
    for (int off = 1; off < 64; off <<= 1) {
        int t = __shfl_up(inc, off, 64);
        if (lane >= off) inc += t;
    }
    int excl = inc - s;
#pragma unroll
    for (int k = 0; k < 5; ++k) cnt[b * NWG + w0 + k] = excl + c[k];
    if (lane == 63) total[b] = excl + s;
}

// ---- pass 2b: exclusive scan over the 625 bin totals
__global__ __launch_bounds__(1024) void k_scanB(const int* __restrict__ total,
                                                int* __restrict__ binStart) {
    __shared__ int tmp[1024];
    int tid = threadIdx.x;
    int v = (tid < NB) ? total[tid] : 0;
    tmp[tid] = v;
    __syncthreads();
    for (int off = 1; off < 1024; off <<= 1) {
        int t = (tid >= off) ? tmp[tid - off] : 0;
        __syncthreads();
        tmp[tid] += t;
        __syncthreads();
    }
    if (tid < NB) binStart[tid] = tmp[tid] - v;
}

// ---- pass 3: place packed edges at exact offsets (LDS cursors; writes stay L2-resident)
__global__ __launch_bounds__(256) void k_place(const int* __restrict__ ei,
                                               const int* __restrict__ cnt,      // excl-scanned
                                               const int* __restrict__ binStart,
                                               unsigned int* __restrict__ bins) {
    __shared__ int cur[NB];
    int tid = threadIdx.x, w = blockIdx.x;
    for (int b = tid; b < NB; b += 256) cur[b] = binStart[b] + cnt[b * NWG + w];
    __syncthreads();
    for (int i = tid; i < CHUNK; i += 256) {
        int ig = w * CHUNK + i;
        int b = ig / TWO_E;
        int j = ig - b * TWO_E;
        int sn = ei[b * TWO_E + j];
        int d4 = b * NNODE + ei[(b + 4) * TWO_E + j];
        unsigned int e = ((unsigned int)d4 << 15) | (unsigned int)sn;
        int pos = atomicAdd(&cur[d4 >> 7], 1);
        bins[pos] = e;
    }
}

// ---- agg1: per-bin LDS accumulation of x0 (3 features) -> agg1f fp32
__global__ __launch_bounds__(256) void k_agg1(const unsigned int* __restrict__ bins,
                                              const int* __restrict__ binStart,
                                              const int* __restrict__ total,
                                              const float* __restrict__ actions,
                                              const float* __restrict__ nf,
                                              float* __restrict__ agg1f) {
    __shared__ float acc[128 * 3];
    int tid = threadIdx.x, bin = blockIdx.x;
    for (int i = tid; i < 384; i += 256) acc[i] = 0.0f;
    __syncthreads();
    int start = binStart[bin], end = start + total[bin];
    const float2* act2 = reinterpret_cast<const float2*>(actions);
    for (int p = start + tid; p < end; p += 256) {
        unsigned int e = bins[p];
        int d4 = e >> 15, sn = e & 0x7FFF;
        int s = (d4 / NNODE) * NNODE + sn;
        float2 a = act2[s];
        float nv = nf[s];
        int r = (d4 & 127) * 3;
        atomicAdd(&acc[r + 0], a.x);
        atomicAdd(&acc[r + 1], a.y);
        atomicAdd(&acc[r + 2], nv);
    }
    __syncthreads();
    for (int i = tid; i < 384; i += 256) agg1f[bin * 384 + i] = acc[i];
}

// ---- conv1 MLP (pure, agg1 pre-computed); x1 stored bf16
__global__ __launch_bounds__(256) void k_conv1(const float* __restrict__ actions,
                                               const float* __restrict__ nf,
                                               const float* __restrict__ agg1f,
                                               const float* __restrict__ w1t, // [128][3]
                                               const float* __restrict__ b1,
                                               const float* __restrict__ w2,  // [128][64]
                                               const float* __restrict__ b2,
                                               unsigned short* __restrict__ x1) {
    int t = blockIdx.x * blockDim.x + threadIdx.x;
    if (t >= BN) return;
    const float2* act2 = reinterpret_cast<const float2*>(actions);
    float2 a = act2[t];
    float h0 = a.x, h1 = a.y, h2 = nf[t];
    if (t >= HN) {
        int d4 = t - HN;
        h0 += agg1f[d4 * 3 + 0];
        h1 += agg1f[d4 * 3 + 1];
        h2 += agg1f[d4 * 3 + 2];
    }

    float acc[64];
#pragma unroll
    for (int o = 0; o < 64; ++o) acc[o] = b2[o];

#pragma unroll 2
    for (int j = 0; j < HID; ++j) {
        float hj = fmaf(h0, w1t[3 * j + 0],
                   fmaf(h1, w1t[3 * j + 1],
                   fmaf(h2, w1t[3 * j + 2], b1[j])));
        hj = fmaxf(hj, 0.0f);
        const float* w2r = w2 + j * 64;
#pragma unroll
        for (int o = 0; o < 64; ++o) acc[o] = fmaf(hj, w2r[o], acc[o]);
    }
    uint4* xo = reinterpret_cast<uint4*>(x1 + (size_t)t * 64);
#pragma unroll
    for (int g = 0; g < 8; ++g) {
        uint4 v;
        v.x = f2bf(fmaxf(acc[8 * g + 0], 0.f)) | ((unsigned int)f2bf(fmaxf(acc[8 * g + 1], 0.f)) << 16);
        v.y = f2bf(fmaxf(acc[8 * g + 2], 0.f)) | ((unsigned int)f2bf(fmaxf(acc[8 * g + 3], 0.f)) << 16);
        v.z = f2bf(fmaxf(acc[8 * g + 4], 0.f)) | ((unsigned int)f2bf(fmaxf(acc[8 * g + 5], 0.f)) << 16);
        v.w = f2bf(fmaxf(acc[8 * g + 6], 0.f)) | ((unsigned int)f2bf(fmaxf(acc[8 * g + 7], 0.f)) << 16);
        xo[g] = v;
    }
}

// ---- agg2 v2: ownership-partitioned, NO LDS atomics.
//      One block per bin, 16 waves; wave w owns dst slots [8w, 8w+8).
//      Every wave scans the bin's edges vectorized (64/lane-load), ballots its owned
//      edges, broadcasts via shfl, does coalesced 128B x1 row reads + plain LDS RMW.
__global__ __launch_bounds__(1024) void k_agg2(const unsigned int* __restrict__ bins,
                                               const int* __restrict__ binStart,
                                               const int* __restrict__ total,
                                               const unsigned short* __restrict__ x1,
                                               unsigned short* __restrict__ agg2) {
    __shared__ float acc[128 * 64];   // 32 KB
    int tid = threadIdx.x, bin = blockIdx.x;
    int lane = tid & 63, wv = tid >> 6;     // 16 waves
    int lo = wv * 8, hi = lo + 8;
    int D0 = bin * 128;
    for (int i = tid; i < 8192; i += 1024) acc[i] = 0.0f;
    __syncthreads();

    int start = binStart[bin], end = start + total[bin];
    for (int base = start; base < end; base += 64) {
        int idx = base + lane;
        unsigned int e = 0xFFFFFFFFu;
        if (idx < end) e = bins[idx];
        int slot = (int)(e >> 15) - D0;              // sentinel -> huge positive
        unsigned long long mask = __ballot(slot >= lo && slot < hi);
        while (mask) {
            int b0 = __builtin_ctzll(mask); mask &= mask - 1;
            bool have2 = (mask != 0);
            int b1 = have2 ? __builtin_ctzll(mask) : b0;
            if (have2) mask &= mask - 1;
            unsigned int e0 = (unsigned int)__shfl((int)e, b0, 64);
            unsigned int e1 = (unsigned int)__shfl((int)e, b1, 64);
            int d0 = (int)(e0 >> 15), d1 = (int)(e1 >> 15);
            int s0 = (d0 / NNODE) * NNODE + (int)(e0 & 0x7FFF);
            int s1 = (d1 / NNODE) * NNODE + (int)(e1 & 0x7FFF);
            float v0 = bf2f(x1[(size_t)s0 * 64 + lane]);
            float v1 = bf2f(x1[(size_t)s1 * 64 + lane]);
            int a0 = (d0 - D0) * 64 + lane;
            int a1 = (d1 - D0) * 64 + lane;
            acc[a0] += v0;                 // plain RMW: this wave exclusively owns its slots
            if (have2) acc[a1] += v1;      // same-address case handled by program order
        }
    }
    __syncthreads();
    for (int i = tid; i < 8192; i += 1024) agg2[(size_t)bin * 8192 + i] = f2bf(acc[i]);
}

// ---- conv2 MLP + global sum pool, MFMA hi/lo (unchanged, verified)
__global__ __launch_bounds__(256) void k_conv2pool(const unsigned short* __restrict__ x1,
                                                   const unsigned short* __restrict__ agg2,
                                                   const unsigned short* __restrict__ w1hi,
                                                   const unsigned short* __restrict__ w1lo,
                                                   const unsigned short* __restrict__ w2hi,
                                                   const unsigned short* __restrict__ w2lo,
                                                   const float* __restrict__ b1,
                                                   const float* __restrict__ b2,
                                                   float* __restrict__ pool) {
    __shared__ __align__(16) unsigned short Hs[32][72];
    __shared__ __align__(16) unsigned short W1s[128][72];
    __shared__ __align__(16) unsigned short Hid[32][136];
    __shared__ __align__(16) unsigned short W2s[64][136];
    __shared__ float poolLDS[64];

    const int tid  = threadIdx.x;
    const int lane = tid & 63;
    const int wv   = tid >> 6;
    const int quad = lane >> 4;
    const int l16  = lane & 15;

    const int m0 = blockIdx.x * 32;
    const int b  = m0 / NNODE;

    if (tid < 64) poolLDS[tid] = 0.0f;

    {
        int row = tid >> 3, g = tid & 7;
        const uint4* xr = reinterpret_cast<const uint4*>(x1 + (size_t)(m0 + row) * 64 + g * 8);
        uint4 v = *xr;
        if (m0 >= HN) {
            const uint4* ar = reinterpret_cast<const uint4*>(agg2 + (size_t)(m0 - HN + row) * 64 + g * 8);
            uint4 a = *ar;
            v.x = addbf2(v.x, a.x); v.y = addbf2(v.y, a.y);
            v.z = addbf2(v.z, a.z); v.w = addbf2(v.w, a.w);
        }
        *reinterpret_cast<uint4*>(&Hs[row][g * 8]) = v;
    }
    for (int i = tid; i < 1024; i += 256) {
        *reinterpret_cast<uint4*>(&W1s[i >> 3][(i & 7) * 8]) =
            reinterpret_cast<const uint4*>(w1hi)[i];
    }
    for (int i = tid; i < 1024; i += 256) {
        *reinterpret_cast<uint4*>(&W2s[i >> 4][(i & 15) * 8]) =
            reinterpret_cast<const uint4*>(w2hi)[i];
    }
    __syncthreads();

    {
        const int mt = wv & 1;
        const int nb = (wv >> 1) * 64;
        f32x4 acc[4];
#pragma unroll
        for (int nt = 0; nt < 4; ++nt) acc[nt] = {0.f, 0.f, 0.f, 0.f};
#pragma unroll
        for (int ks = 0; ks < 2; ++ks) {
            bf16x8 a = *reinterpret_cast<const bf16x8*>(&Hs[mt * 16 + l16][ks * 32 + quad * 8]);
#pragma unroll
            for (int nt = 0; nt < 4; ++nt) {
                int fid = ((nb >> 4) + nt) * 2 + ks;
                bf16x8 bhi = *reinterpret_cast<const bf16x8*>(&W1s[nb + nt * 16 + l16][ks * 32 + quad * 8]);
                bf16x8 blo = *reinterpret_cast<const bf16x8*>(&w1lo[(size_t)(fid * 64 + lane) * 8]);
                acc[nt] = __builtin_amdgcn_mfma_f32_16x16x32_bf16(a, bhi, acc[nt], 0, 0, 0);
                acc[nt] = __builtin_amdgcn_mfma_f32_16x16x32_bf16(a, blo, acc[nt], 0, 0, 0);
            }
        }
#pragma unroll
        for (int nt = 0; nt < 4; ++nt) {
            int n = nb + nt * 16 + l16;
            float bias = b1[n];
#pragma unroll
            for (int r = 0; r < 4; ++r) {
                int m = mt * 16 + quad * 4 + r;
                Hid[m][n] = f2bf(fmaxf(acc[nt][r] + bias, 0.0f));
            }
        }
    }
    __syncthreads();

    {
        const int mt = wv & 1;
        const int nb = (wv >> 1) * 32;
        f32x4 acc[2];
#pragma unroll
        for (int nt = 0; nt < 2; ++nt) acc[nt] = {0.f, 0.f, 0.f, 0.f};
#pragma unroll
        for (int ks = 0; ks < 4; ++ks) {
            bf16x8 a = *reinterpret_cast<const bf16x8*>(&Hid[mt * 16 + l16][ks * 32 + quad * 8]);
#pragma unroll
            for (int nt = 0; nt < 2; ++nt) {
                int fid = ((nb >> 4) + nt) * 4 + ks;
                bf16x8 bhi = *reinterpret_cast<const bf16x8*>(&W2s[nb + nt * 16 + l16][ks * 32 + quad * 8]);
                bf16x8 blo = *reinterpret_cast<const bf16x8*>(&w2lo[(size_t)(fid * 64 + lane) * 8]);
                acc[nt] = __builtin_amdgcn_mfma_f32_16x16x32_bf16(a, bhi, acc[nt], 0, 0, 0);
                acc[nt] = __builtin_amdgcn_mfma_f32_16x16x32_bf16(a, blo, acc[nt], 0, 0, 0);
            }
        }
#pragma unroll
        for (int nt = 0; nt < 2; ++nt) {
            int n = nb + nt * 16 + l16;
            float bias = b2[n];
            float p = 0.0f;
#pragma unroll
            for (int r = 0; r < 4; ++r) p += fmaxf(acc[nt][r] + bias, 0.0f);
            p += __shfl_xor(p, 16, 64);
            p += __shfl_xor(p, 32, 64);
            if (lane < 16) atomicAdd(&poolLDS[n], p);
        }
    }
    __syncthreads();

    if (tid < 64) atomicAdd(&pool[b * 64 + tid], poolLDS[tid]);
}

// ---- q = relu(pool @ mlp_w + mlp_b)  [8,128]
__global__ __launch_bounds__(128) void k_q(const float* __restrict__ pool,
                                           const float* __restrict__ mlp_w,
                                           const float* __restrict__ mlp_b,
                                           float* __restrict__ q) {
    int j = threadIdx.x;
    for (int b = 0; b < NBATCH; ++b) {
        float a = mlp_b[j];
#pragma unroll 8
        for (int k = 0; k < 64; ++k) a = fmaf(pool[b * 64 + k], mlp_w[k * 128 + j], a);
        q[b * 128 + j] = fmaxf(a, 0.0f);
    }
}

// ---- out = sigmoid(q @ out_w + out_b): 625 blocks x (8 batches x 32 cols);
//      out_w fetched once total (each column used by all 8 batches in-block).
__global__ __launch_bounds__(256) void k_out(const float* __restrict__ q,
                                             const float* __restrict__ out_w, // [128][20000]
                                             const float* __restrict__ out_b,
                                             float* __restrict__ out) {
    __shared__ float qs[NBATCH][128];
    int tid = threadIdx.x;
    for (int i = tid; i < NBATCH * 128; i += 256) qs[i >> 7][i & 127] = q[i];
    __syncthreads();
    int c = tid & 31, b = tid >> 5;                  // 8 batches x 32 columns
    int n = blockIdx.x * 32 + c;
    const float* qr = qs[b];
    float a = out_b[n];
#pragma unroll 8
    for (int j = 0; j < 128; ++j) a = fmaf(qr[j], out_w[j * NNODE + n], a);
    out[b * NNODE + n] = 1.0f / (1.0f + expf(-a));
}

extern "C" void kernel_launch(void* const* d_in, const int* in_sizes, int n_in,
                              void* d_out, int out_size, void* d_ws, size_t ws_size,
                              hipStream_t stream) {
    const float* actions = (const float*)d_in[0];
    const float* nf      = (const float*)d_in[1];
    const int*   ei      = (const int*)d_in[2];
    const float* c1_w1   = (const float*)d_in[3];
    const float* c1_b1   = (const float*)d_in[4];
    const float* c1_w2   = (const float*)d_in[5];
    const float* c1_b2   = (const float*)d_in[6];
    const float* c2_w1   = (const float*)d_in[7];
    const float* c2_b1   = (const float*)d_in[8];
    const float* c2_w2   = (const float*)d_in[9];
    const float* c2_b2   = (const float*)d_in[10];
    const float* mlp_w   = (const float*)d_in[11];
    const float* mlp_b   = (const float*)d_in[12];
    const float* out_w   = (const float*)d_in[13];
    const float* out_b   = (const float*)d_in[14];
    float* out = (float*)d_out;

    char* ws = (char*)d_ws;
    float*        pool     = (float*)(ws + OFF_POOL);
    int*          cnt      = (int*)(ws + OFF_CNT);
    int*          total    = (int*)(ws + OFF_TOTAL);
    int*          binStart = (int*)(ws + OFF_BSTART);
    unsigned int* bins     = (unsigned int*)(ws + OFF_BINS);
    float*        agg1f    = (float*)(ws + OFF_AGG1F);
    unsigned short* agg2   = (unsigned short*)(ws + OFF_AGG2);
    unsigned short* x1     = (unsigned short*)(ws + OFF_X1);
    float* w1t1 = (float*)(ws + OFF_W1T1);
    unsigned short* w1hi = (unsigned short*)(ws + OFF_W1HI);
    unsigned short* w2hi = (unsigned short*)(ws + OFF_W2HI);
    unsigned short* w1lo = (unsigned short*)(ws + OFF_W1LO);
    unsigned short* w2lo = (unsigned short*)(ws + OFF_W2LO);
    float* q = (float*)(ws + OFF_Q);

    hipMemsetAsync(d_ws, 0, ZERO_BYTES, stream);   // pool only

    k_transpose<<<32, 256, 0, stream>>>(c1_w1, c2_w1, c2_w2, w1t1, w1hi, w2hi, w1lo, w2lo);

    // counting-sort of edges into 625 dst bins (exact offsets)
    k_hist <<<NWG, 256, 0, stream>>>(ei, cnt);
    k_scanA<<<NB, 64, 0, stream>>>(cnt, total);
    k_scanB<<<1, 1024, 0, stream>>>(total, binStart);
    k_place<<<NWG, 256, 0, stream>>>(ei, cnt, binStart, bins);

    // aggregations from sorted bins, then MLPs
    k_agg1<<<NB, 256, 0, stream>>>(bins, binStart, total, actions, nf, agg1f);
    k_conv1<<<BN / 256, 256, 0, stream>>>(actions, nf, agg1f, w1t1, c1_b1, c1_w2, c1_b2, x1);
    k_agg2<<<NB, 1024, 0, stream>>>(bins, binStart, total, x1, agg2);

    k_conv2pool<<<BN / 32, 256, 0, stream>>>(x1, agg2, w1hi, w1lo, w2hi, w2lo,
                                             c2_b1, c2_b2, pool);

    k_q<<<1, 128, 0, stream>>>(pool, mlp_w, mlp_b, q);
    k_out<<<NNODE / 32, 256, 0, stream>>>(q, out_w, out_b, out);
}